// Round 12
// baseline (835.470 us; speedup 1.0000x reference)
//
#include <hip/hip_runtime.h>
#include <hip/hip_fp16.h>

#define TT 100
#define BB 4096
#define GS 488   // floats per batch blob; 4 blobs/block at mod-32 offsets 0,8,16,24

// per-batch float layout:
//   V   [0,144)    12x12 value matrix, stored transposed (V[l*12+i]=Vn[i][l]);
//                  read as rows via symmetry (proven R11)
//   Fl  [144,384)  12 rows x stride 20
//   vv  [384,396)  v
//   tb  [396,428)  ft (backward) / 2x16 tau ping-pong (forward)
//
// Lane layout (R12): batch = ONE 64-lane wave. lane = 4*l + qd:
//   l  = lane>>2  : column 0..15
//   qd = lane&3   : quarter; owns s,i ranges [3qd,3qd+3)
// Quarter-sums: DPP quad_perm (VALU). Quu/qu: v_readlane (const lanes).
// Qxu: 12 bpermute shfls. => ONE lgkm fence per backward step.

#define FENCE() asm volatile("s_waitcnt lgkmcnt(0)" ::: "memory")

// sum over the 4 lanes of own quad (lanes 4l..4l+3) — pure VALU
__device__ __forceinline__ float quadsum(float x){
  int a = __builtin_amdgcn_update_dpp(0, __float_as_int(x), 0xB1, 0xF, 0xF, true); // [1,0,3,2]
  x += __int_as_float(a);
  int c = __builtin_amdgcn_update_dpp(0, __float_as_int(x), 0x4E, 0xF, 0xF, true); // [2,3,0,1]
  x += __int_as_float(c);
  return x;
}
__device__ __forceinline__ float readlanef(float x, int srclane){
  return __int_as_float(__builtin_amdgcn_readlane(__float_as_int(x), srclane));
}
// 16-lane rotate-add reduce (row 0) — proven R8-R11
template<int CTRL>
__device__ __forceinline__ float ror_add(float x){
  int r = __builtin_amdgcn_update_dpp(0, __float_as_int(x), CTRL, 0xF, 0xF, true);
  return x + __int_as_float(r);
}
__device__ __forceinline__ float reduce16_dpp(float x){
  x = ror_add<0x128>(x); x = ror_add<0x124>(x);
  x = ror_add<0x122>(x); x = ror_add<0x121>(x);
  return x;
}

template<int KMODE>
__device__ __forceinline__ void storeK(void* wsv, size_t of, int l, float X0,float X1,float X2,float X3){
  if (KMODE==0){
    float* wsb=(float*)wsv + of*52;
    if (l<12)       ((float4*)wsb)[l]  = make_float4(X0,X1,X2,X3);
    else if (l==12) ((float4*)wsb)[12] = make_float4(X0,X1,X2,X3);
  } else {
    __half* wsb=(__half*)wsv + of*52;
    if (l<12){
      wsb[l*4+0]=__float2half(X0); wsb[l*4+1]=__float2half(X1);
      wsb[l*4+2]=__float2half(X2); wsb[l*4+3]=__float2half(X3);
    } else if (l==12){
      wsb[48]=__float2half(X0); wsb[49]=__float2half(X1);
      wsb[50]=__float2half(X2); wsb[51]=__float2half(X3);
    }
  }
}
template<int KMODE>
__device__ __forceinline__ float4 loadKcol(const void* wsv, size_t of, int l){
  if (KMODE==0) return ((const float4*)((const float*)wsv + of*52))[l];
  const __half* p=(const __half*)wsv + of*52 + l*4;
  return make_float4(__half2float(p[0]),__half2float(p[1]),__half2float(p[2]),__half2float(p[3]));
}
template<int KMODE>
__device__ __forceinline__ float loadkk(const void* wsv, size_t of, int r){
  if (KMODE==0) return ((const float*)wsv)[of*52+48+r];
  return __half2float(((const __half*)wsv)[of*52+48+r]);
}

template<int KMODE>
__global__ __launch_bounds__(256,4)
void lqr_fused(const float* __restrict__ xinit,
               const float* __restrict__ Cg,
               const float* __restrict__ cg,
               const float* __restrict__ Fg,
               const float* __restrict__ fg,
               float* __restrict__ out,
               void* __restrict__ wsv)
{
  __shared__ float smem[GS*4];
  const int tid  = threadIdx.x;
  const int lane = tid & 63;
  const int wv   = tid >> 6;          // wave (=batch) within block
  const int b    = blockIdx.x*4 + wv;
  const int l    = lane >> 2;         // column
  const int qd   = lane & 3;          // quarter

  float* __restrict__ Vb = smem + wv*GS;
  float* __restrict__ Fl = Vb + 144;
  float* __restrict__ vv = Vb + 384;
  float* __restrict__ tb = Vb + 396;

  // zero V (each lane: its 3 i's of column l) and vv
  if (l<12){
    const int i0=3*qd;
    Vb[l*12+i0]=0.f; Vb[l*12+i0+1]=0.f; Vb[l*12+i0+2]=0.f;
    if (qd==0) vv[l]=0.f;
  }

  // ================= backward Riccati =================
  float4 sC0,sC1,sC2,sC3; float sc_;
  float4 sFst=make_float4(0,0,0,0); float sftv=0.f;
  {
    const size_t of = ((size_t)(TT-1)*BB + b);
    const float4* pc=(const float4*)(Cg + of*256 + l*16);
    sC0=pc[0];sC1=pc[1];sC2=pc[2];sC3=pc[3];   // full C column l (via symmetry)
    sc_=cg[of*16+l];
  }

  for (int tt=TT-1; tt>=0; --tt){
    const bool hasF = (tt < TT-1);
    float4 C0=sC0,C1=sC1,C2=sC2,C3=sC3; float rc=sc_;
    float4 Fst=sFst; float ftv=sftv;

    if (hasF){
      if (lane<48) *(float4*)(Fl + l*20 + 4*qd) = Fst;  // row l, cols [4qd,4qd+4)
      if (qd==0 && l<12) tb[l]=ftv;
    }
    FENCE(); // the ONLY backward fence: F/ft staged; prev-iter V/vv visible;
             // prev-iter LDS reads drained (WAR for the Fl overwrite)

    if (tt>0){
      const size_t of = ((size_t)(tt-1)*BB + b);
      const float4* pc=(const float4*)(Cg + of*256 + l*16);
      sC0=pc[0];sC1=pc[1];sC2=pc[2];sC3=pc[3];
      sc_=cg[of*16+l];
      if (lane<48) sFst = ((const float4*)(Fg + of*192))[lane]; // row l, col 4qd
      if (qd==0 && l<12) sftv = fg[of*12+l];
    }

    float Qf[16]={0,0,0,0,0,0,0,0,0,0,0,0,0,0,0,0};
    float qf=0.f;
    if (hasF){
      float Ftj[12];
      #pragma unroll
      for (int t=0;t<12;t++) Ftj[t]=Fl[t*20+l];   // F column l
      const int s0=3*qd;
      float W[3];
      #pragma unroll
      for (int j=0;j<3;j++){
        const float4* vr=(const float4*)(Vb+(s0+j)*12);
        float4 v0=vr[0],v1=vr[1],v2=vr[2];
        W[j]= v0.x*Ftj[0]+v0.y*Ftj[1]+v0.z*Ftj[2]+v0.w*Ftj[3]
            + v1.x*Ftj[4]+v1.y*Ftj[5]+v1.z*Ftj[6]+v1.w*Ftj[7]
            + v2.x*Ftj[8]+v2.y*Ftj[9]+v2.z*Ftj[10]+v2.w*Ftj[11];
      }
      #pragma unroll
      for (int j=0;j<3;j++){
        const float4* fr=(const float4*)(Fl+(s0+j)*20);
        float4 f0=fr[0],f1=fr[1],f2=fr[2],f3=fr[3];
        const float w=W[j];
        Qf[0]+=f0.x*w;  Qf[1]+=f0.y*w;  Qf[2]+=f0.z*w;  Qf[3]+=f0.w*w;
        Qf[4]+=f1.x*w;  Qf[5]+=f1.y*w;  Qf[6]+=f1.z*w;  Qf[7]+=f1.w*w;
        Qf[8]+=f2.x*w;  Qf[9]+=f2.y*w;  Qf[10]+=f2.z*w; Qf[11]+=f2.w*w;
        Qf[12]+=f3.x*w; Qf[13]+=f3.y*w; Qf[14]+=f3.z*w; Qf[15]+=f3.w*w;
        qf += w*tb[s0+j];
      }
      // static-index selects for Ftj[3qd+j] (rule #20)
      const float fta = qd==0?Ftj[0]:qd==1?Ftj[3]:qd==2?Ftj[6]:Ftj[9];
      const float ftb = qd==0?Ftj[1]:qd==1?Ftj[4]:qd==2?Ftj[7]:Ftj[10];
      const float ftc = qd==0?Ftj[2]:qd==1?Ftj[5]:qd==2?Ftj[8]:Ftj[11];
      qf += fta*vv[s0] + ftb*vv[s0+1] + ftc*vv[s0+2];
    }

    // full Q column on every lane: VALU quad-sum + C
    const float Cr[16]={C0.x,C0.y,C0.z,C0.w, C1.x,C1.y,C1.z,C1.w,
                        C2.x,C2.y,C2.z,C2.w, C3.x,C3.y,C3.z,C3.w};
    float Qc[16];
    #pragma unroll
    for (int i=0;i<16;i++) Qc[i] = Cr[i] + quadsum(Qf[i]);
    const float qv = rc + quadsum(qf);

    // Quu/qu via readlane from columns 12..15 (lanes 48,52,56,60) -> SGPRs
    float a00=readlanef(Qc[12],48),a01=readlanef(Qc[12],52),a02=readlanef(Qc[12],56),a03=readlanef(Qc[12],60);
    float a10=readlanef(Qc[13],48),a11=readlanef(Qc[13],52),a12=readlanef(Qc[13],56),a13=readlanef(Qc[13],60);
    float a20=readlanef(Qc[14],48),a21=readlanef(Qc[14],52),a22=readlanef(Qc[14],56),a23=readlanef(Qc[14],60);
    float a30=readlanef(Qc[15],48),a31=readlanef(Qc[15],52),a32=readlanef(Qc[15],56),a33=readlanef(Qc[15],60);
    const float qu0=readlanef(qv,48),qu1=readlanef(qv,52),qu2=readlanef(qv,56),qu3=readlanef(qv,60);

    // K RHS (per-lane, valid for l<12; others unused)
    float b0=-Qc[12],b1=-Qc[13],b2=-Qc[14],b3=-Qc[15];
    // 4x4 LU, no pivot (Quu SPD, diag >= 1); factor is wave-uniform
    const float i0=1.0f/a00;
    const float m10=a10*i0,m20=a20*i0,m30=a30*i0;
    a11-=m10*a01;a12-=m10*a02;a13-=m10*a03;
    a21-=m20*a01;a22-=m20*a02;a23-=m20*a03;
    a31-=m30*a01;a32-=m30*a02;a33-=m30*a03;
    b1-=m10*b0;b2-=m20*b0;b3-=m30*b0;
    const float i1=1.0f/a11;
    const float m21=a21*i1,m31=a31*i1;
    a22-=m21*a12;a23-=m21*a13;
    a32-=m31*a12;a33-=m31*a13;
    b2-=m21*b1;b3-=m31*b1;
    const float i2=1.0f/a22;
    const float m32=a32*i2;
    a33-=m32*a23;
    b3-=m32*b2;
    const float X3=b3/a33;
    const float X2=(b2-a23*X3)*i2;
    const float X1=(b1-a12*X2-a13*X3)*i1;
    const float X0=(b0-a01*X1-a02*X2-a03*X3)*i0;
    // k RHS (uniform)
    float c0=-qu0,c1=-qu1,c2=-qu2,c3=-qu3;
    c1-=m10*c0;c2-=m20*c0;c3-=m30*c0;
    c2-=m21*c1;c3-=m31*c1;
    c3-=m32*c2;
    const float k3=c3/a33;
    const float k2v=(c2-a23*k3)*i2;
    const float k1=(c1-a12*k2v-a13*k3)*i1;
    const float k0=(c0-a01*k1-a02*k2v-a03*k3)*i0;

    if (qd==0)
      storeK<KMODE>(wsv, (size_t)tt*BB+b, l,
                    l<12?X0:k0, l<12?X1:k1, l<12?X2:k2v, l<12?X3:k3);

    // Vn: base_j = Qc[3qd+j] (select, static idx); Qxu via shfl from
    // lane 48+4r+qd (its base_j == Q[3qd+j][12+r])
    const float base0 = qd==0?Qc[0]:qd==1?Qc[3]:qd==2?Qc[6]:Qc[9];
    const float base1 = qd==0?Qc[1]:qd==1?Qc[4]:qd==2?Qc[7]:Qc[10];
    const float base2 = qd==0?Qc[2]:qd==1?Qc[5]:qd==2?Qc[8]:Qc[11];
    float vn0=base0, vn1=base1, vn2=base2;
    #pragma unroll
    for (int r=0;r<4;r++){
      const float Xr = r==0?X0:r==1?X1:r==2?X2:X3;
      vn0 += __shfl(base0, 48+4*r+qd, 64) * Xr;
      vn1 += __shfl(base1, 48+4*r+qd, 64) * Xr;
      vn2 += __shfl(base2, 48+4*r+qd, 64) * Xr;
    }
    if (l<12){
      const int i0i=3*qd;
      Vb[l*12+i0i]=vn0; Vb[l*12+i0i+1]=vn1; Vb[l*12+i0i+2]=vn2;
      if (qd==0)
        vv[l] = qv + Qc[12]*k0 + Qc[13]*k1 + Qc[14]*k2v + Qc[15]*k3;
    }
    // V/vv/Fl hazards vs next iter: covered by next iter's FENCE
  }

  // drain K/k global stores before forward reads them
  asm volatile("s_waitcnt vmcnt(0)" ::: "memory");

  // ================= forward rollout (quarter-indexed) =================
  const int fl = lane & 15;      // column
  const int g4 = lane >> 4;      // row-quarter (group 0 = lanes 0-15)

  float xj = (g4==0 && fl<12)? xinit[(size_t)b*12+fl] : 0.f;
  double costacc=0.0;

  float4 sCa; float sc2_;
  float4 sF0=make_float4(0,0,0,0),sF1=sF0,sF2=sF0,sF3=sF0; float sf_=0.f;
  float4 sK=make_float4(0,0,0,0); float sk_=0.f;
  {
    const float4* pc=(const float4*)(Cg + (size_t)b*256 + fl*16);
    sCa=pc[g4];                      // C col fl, rows [4g4,4g4+4)
    sc2_=cg[(size_t)b*16+fl];
    if (g4==0 && fl<12){
      const float4* pf=(const float4*)(Fg + (size_t)b*192 + fl*16);
      sF0=pf[0];sF1=pf[1];sF2=pf[2];sF3=pf[3];
      sf_=fg[(size_t)b*12+fl];
      sK=loadKcol<KMODE>(wsv,(size_t)b,fl);
    }
    if (g4==0 && fl>=12) sk_=loadkk<KMODE>(wsv,(size_t)b,fl-12);
  }

  for (int t=0;t<TT;t++){
    float4 Ca=sCa; float rc=sc2_;
    float4 F0=sF0,F1=sF1,F2=sF2,F3=sF3; float rf=sf_;
    float4 K4=sK; float kl=sk_;

    if (t+1<TT){
      const size_t of=((size_t)(t+1)*BB + b);
      const float4* pc=(const float4*)(Cg + of*256 + fl*16);
      sCa=pc[g4];
      sc2_=cg[of*16+fl];
      if (g4==0 && fl<12){
        sK=loadKcol<KMODE>(wsv,of,fl);
        if (t+1<TT-1){
          const float4* pf=(const float4*)(Fg + of*192 + fl*16);
          sF0=pf[0];sF1=pf[1];sF2=pf[2];sF3=pf[3];
          sf_=fg[of*12+fl];
        }
      }
      if (g4==0 && fl>=12) sk_=loadkk<KMODE>(wsv,of,fl-12);
    }

    // u = K x + k : 16-lane DPP reduce on row 0 (lanes 0-15)
    float pr0=0.f,pr1=0.f,pr2=0.f,pr3=0.f;
    if (g4==0 && fl<12){ pr0=K4.x*xj; pr1=K4.y*xj; pr2=K4.z*xj; pr3=K4.w*xj; }
    pr0=reduce16_dpp(pr0); pr1=reduce16_dpp(pr1);
    pr2=reduce16_dpp(pr2); pr3=reduce16_dpp(pr3);

    float* tbuf = tb + (t&1)*16;
    float tauj=0.f;
    if (g4==0){
      if (fl<12) tauj=xj;
      else {
        const float ur=(fl==12)?pr0:(fl==13)?pr1:(fl==14)?pr2:pr3;
        tauj=ur+kl;
      }
      tbuf[fl]=tauj;
    }
    FENCE(); // tau staged (hardware fence: R8 lesson)

    const float taul = tbuf[fl];
    const float4 tq = ((const float4*)tbuf)[g4];    // tau rows [4g4,4g4+4)

    // cost partial: 0.5*tau_fl * sum_{j in quarter} C[j][fl] tau_j (+ c term on g4==0)
    const float dot_p = Ca.x*tq.x + Ca.y*tq.y + Ca.z*tq.z + Ca.w*tq.w;
    costacc += (double)( taul*0.5f*dot_p + (g4==0 ? taul*rc : 0.f) );

    if (g4==0){
      if (fl<12) out[(size_t)t*BB*12 + (size_t)b*12 + fl] = xj;
      else       out[(size_t)TT*BB*12 + (size_t)t*BB*4 + (size_t)b*4 + (fl-12)] = tauj;
    }

    if (t<TT-1 && g4==0 && fl<12){
      const float4* tp=(const float4*)tbuf;
      const float4 t0=tp[0],t1=tp[1],t2=tp[2],t3=tp[3];
      xj = rf
         + F0.x*t0.x+F0.y*t0.y+F0.z*t0.z+F0.w*t0.w
         + F1.x*t1.x+F1.y*t1.y+F1.z*t1.z+F1.w*t1.w
         + F2.x*t2.x+F2.y*t2.y+F2.z*t2.z+F2.w*t2.w
         + F3.x*t3.x+F3.y*t3.y+F3.z*t3.z+F3.w*t3.w;
    }
    // tau WAR across iters: ping-pong
  }

  costacc+=__shfl_xor(costacc,1,64);  costacc+=__shfl_xor(costacc,2,64);
  costacc+=__shfl_xor(costacc,4,64);  costacc+=__shfl_xor(costacc,8,64);
  costacc+=__shfl_xor(costacc,16,64); costacc+=__shfl_xor(costacc,32,64);
  if (lane==0) out[(size_t)TT*BB*16 + b]=(float)costacc;
}

extern "C" void kernel_launch(void* const* d_in, const int* in_sizes, int n_in,
                              void* d_out, int out_size, void* d_ws, size_t ws_size,
                              hipStream_t stream){
  (void)in_sizes; (void)n_in; (void)out_size;
  const float* xinit=(const float*)d_in[0];
  const float* C    =(const float*)d_in[1];
  const float* c    =(const float*)d_in[2];
  const float* F    =(const float*)d_in[3];
  const float* f    =(const float*)d_in[4];
  const size_t need_f32 = (size_t)TT*BB*52*sizeof(float);   // 85.2 MB
  if (ws_size >= need_f32){
    lqr_fused<0><<<dim3(BB/4), dim3(256), 0, stream>>>(xinit,C,c,F,f,(float*)d_out,d_ws);
  } else {
    lqr_fused<1><<<dim3(BB/4), dim3(256), 0, stream>>>(xinit,C,c,F,f,(float*)d_out,d_ws);
  }
}

// Round 13
// 463.667 us; speedup vs baseline: 1.8019x; 1.8019x over previous
//
#include <hip/hip_runtime.h>
#include <hip/hip_fp16.h>

#define TT 100
#define BB 4096
#define GS 488   // floats per batch blob; 4 blobs/block at mod-32 offsets 0,8,16,24

// per-batch float layout:
//   V   [0,144)    12x12 value matrix, stored transposed (V[l*12+i]=Vn[i][l]);
//                  read as rows via symmetry (proven R11/R12)
//   Fl  [144,384)  12 rows x stride 20
//   vv  [384,396)  v
//   tb  [396,428)  ft (backward) / 2x16 tau ping-pong (forward)
//
// Lane layout (R12/R13): batch = ONE 64-lane wave. lane = 4*l + qd:
//   l  = lane>>2  : column 0..15
//   qd = lane&3   : quarter; owns s,i ranges [3qd,3qd+3), C rows [4qd,4qd+4)
// Quarter-sums: DPP quad_perm (VALU). Quu/qu: v_readlane (wave-uniform lanes).
// Qxu: 12 bpermute shfls. => ONE lgkm fence per backward step.
//
// R13 vs R12: spill fix. (1) no launch_bounds min-waves arg (R12's ",4" drove
// the allocator to 64 VGPR -> ~1 GB/dispatch scratch traffic); (2) C loaded
// as per-lane QUARTER column (1 float4, coalesced) folded into Qf init;
// Cr[16]/Qc[16] replicas eliminated (Qc overwrites Qf in place).

#define FENCE() asm volatile("s_waitcnt lgkmcnt(0)" ::: "memory")

// sum over the 4 lanes of own quad (lanes 4l..4l+3) — pure VALU
__device__ __forceinline__ float quadsum(float x){
  int a = __builtin_amdgcn_update_dpp(0, __float_as_int(x), 0xB1, 0xF, 0xF, true); // [1,0,3,2]
  x += __int_as_float(a);
  int c = __builtin_amdgcn_update_dpp(0, __float_as_int(x), 0x4E, 0xF, 0xF, true); // [2,3,0,1]
  x += __int_as_float(c);
  return x;
}
__device__ __forceinline__ float readlanef(float x, int srclane){
  return __int_as_float(__builtin_amdgcn_readlane(__float_as_int(x), srclane));
}
// 16-lane rotate-add reduce — proven R8-R12
template<int CTRL>
__device__ __forceinline__ float ror_add(float x){
  int r = __builtin_amdgcn_update_dpp(0, __float_as_int(x), CTRL, 0xF, 0xF, true);
  return x + __int_as_float(r);
}
__device__ __forceinline__ float reduce16_dpp(float x){
  x = ror_add<0x128>(x); x = ror_add<0x124>(x);
  x = ror_add<0x122>(x); x = ror_add<0x121>(x);
  return x;
}

template<int KMODE>
__device__ __forceinline__ void storeK(void* wsv, size_t of, int l, float X0,float X1,float X2,float X3){
  if (KMODE==0){
    float* wsb=(float*)wsv + of*52;
    if (l<12)       ((float4*)wsb)[l]  = make_float4(X0,X1,X2,X3);
    else if (l==12) ((float4*)wsb)[12] = make_float4(X0,X1,X2,X3);
  } else {
    __half* wsb=(__half*)wsv + of*52;
    if (l<12){
      wsb[l*4+0]=__float2half(X0); wsb[l*4+1]=__float2half(X1);
      wsb[l*4+2]=__float2half(X2); wsb[l*4+3]=__float2half(X3);
    } else if (l==12){
      wsb[48]=__float2half(X0); wsb[49]=__float2half(X1);
      wsb[50]=__float2half(X2); wsb[51]=__float2half(X3);
    }
  }
}
template<int KMODE>
__device__ __forceinline__ float4 loadKcol(const void* wsv, size_t of, int l){
  if (KMODE==0) return ((const float4*)((const float*)wsv + of*52))[l];
  const __half* p=(const __half*)wsv + of*52 + l*4;
  return make_float4(__half2float(p[0]),__half2float(p[1]),__half2float(p[2]),__half2float(p[3]));
}
template<int KMODE>
__device__ __forceinline__ float loadkk(const void* wsv, size_t of, int r){
  if (KMODE==0) return ((const float*)wsv)[of*52+48+r];
  return __half2float(((const __half*)wsv)[of*52+48+r]);
}

template<int KMODE>
__global__ __launch_bounds__(256)
void lqr_fused(const float* __restrict__ xinit,
               const float* __restrict__ Cg,
               const float* __restrict__ cg,
               const float* __restrict__ Fg,
               const float* __restrict__ fg,
               float* __restrict__ out,
               void* __restrict__ wsv)
{
  __shared__ float smem[GS*4];
  const int tid  = threadIdx.x;
  const int lane = tid & 63;
  const int wv   = tid >> 6;          // wave (=batch) within block
  const int b    = blockIdx.x*4 + wv;
  const int l    = lane >> 2;         // column
  const int qd   = lane & 3;          // quarter

  float* __restrict__ Vb = smem + wv*GS;
  float* __restrict__ Fl = Vb + 144;
  float* __restrict__ vv = Vb + 384;
  float* __restrict__ tb = Vb + 396;

  // zero V (each lane: its 3 i's of column l) and vv
  if (l<12){
    const int i0=3*qd;
    Vb[l*12+i0]=0.f; Vb[l*12+i0+1]=0.f; Vb[l*12+i0+2]=0.f;
    if (qd==0) vv[l]=0.f;
  }

  // ================= backward Riccati =================
  float4 sCq; float sc_;
  float4 sFst=make_float4(0,0,0,0); float sftv=0.f;
  {
    const size_t of = ((size_t)(TT-1)*BB + b);
    sCq = ((const float4*)(Cg + of*256 + l*16))[qd];   // C col l, rows [4qd,4qd+4)
    sc_ = cg[of*16+l];
  }

  for (int tt=TT-1; tt>=0; --tt){
    const bool hasF = (tt < TT-1);
    const float4 Cq=sCq; const float rc=sc_;
    const float4 Fst=sFst; const float ftv=sftv;

    if (hasF){
      if (lane<48) *(float4*)(Fl + l*20 + 4*qd) = Fst;  // row l, cols [4qd,4qd+4)
      if (qd==0 && l<12) tb[l]=ftv;
    }
    FENCE(); // the ONLY backward fence: F/ft staged; prev-iter V/vv visible

    if (tt>0){
      const size_t of = ((size_t)(tt-1)*BB + b);
      sCq = ((const float4*)(Cg + of*256 + l*16))[qd];
      sc_ = cg[of*16+l];
      if (lane<48) sFst = ((const float4*)(Fg + of*192))[lane];
      if (qd==0 && l<12) sftv = fg[of*12+l];
    }

    // Qf: partial Q column; C quarter folded into init (predicated, static idx)
    float Qf[16];
    {
      const float cx=Cq.x, cy=Cq.y, cz=Cq.z, cw=Cq.w;
      Qf[0] =(qd==0)?cx:0.f; Qf[1] =(qd==0)?cy:0.f; Qf[2] =(qd==0)?cz:0.f; Qf[3] =(qd==0)?cw:0.f;
      Qf[4] =(qd==1)?cx:0.f; Qf[5] =(qd==1)?cy:0.f; Qf[6] =(qd==1)?cz:0.f; Qf[7] =(qd==1)?cw:0.f;
      Qf[8] =(qd==2)?cx:0.f; Qf[9] =(qd==2)?cy:0.f; Qf[10]=(qd==2)?cz:0.f; Qf[11]=(qd==2)?cw:0.f;
      Qf[12]=(qd==3)?cx:0.f; Qf[13]=(qd==3)?cy:0.f; Qf[14]=(qd==3)?cz:0.f; Qf[15]=(qd==3)?cw:0.f;
    }
    float qf=0.f;
    if (hasF){
      float Ftj[12];
      #pragma unroll
      for (int t=0;t<12;t++) Ftj[t]=Fl[t*20+l];   // F column l
      const int s0=3*qd;
      float W[3];
      #pragma unroll
      for (int j=0;j<3;j++){
        const float4* vr=(const float4*)(Vb+(s0+j)*12);
        float4 v0=vr[0],v1=vr[1],v2=vr[2];
        W[j]= v0.x*Ftj[0]+v0.y*Ftj[1]+v0.z*Ftj[2]+v0.w*Ftj[3]
            + v1.x*Ftj[4]+v1.y*Ftj[5]+v1.z*Ftj[6]+v1.w*Ftj[7]
            + v2.x*Ftj[8]+v2.y*Ftj[9]+v2.z*Ftj[10]+v2.w*Ftj[11];
      }
      #pragma unroll
      for (int j=0;j<3;j++){
        const float4* fr=(const float4*)(Fl+(s0+j)*20);
        float4 f0=fr[0],f1=fr[1],f2=fr[2],f3=fr[3];
        const float w=W[j];
        Qf[0]+=f0.x*w;  Qf[1]+=f0.y*w;  Qf[2]+=f0.z*w;  Qf[3]+=f0.w*w;
        Qf[4]+=f1.x*w;  Qf[5]+=f1.y*w;  Qf[6]+=f1.z*w;  Qf[7]+=f1.w*w;
        Qf[8]+=f2.x*w;  Qf[9]+=f2.y*w;  Qf[10]+=f2.z*w; Qf[11]+=f2.w*w;
        Qf[12]+=f3.x*w; Qf[13]+=f3.y*w; Qf[14]+=f3.z*w; Qf[15]+=f3.w*w;
        qf += w*tb[s0+j];
      }
      // static-index selects for Ftj[3qd+j] (rule #20)
      const float fta = qd==0?Ftj[0]:qd==1?Ftj[3]:qd==2?Ftj[6]:Ftj[9];
      const float ftb = qd==0?Ftj[1]:qd==1?Ftj[4]:qd==2?Ftj[7]:Ftj[10];
      const float ftc = qd==0?Ftj[2]:qd==1?Ftj[5]:qd==2?Ftj[8]:Ftj[11];
      qf += fta*vv[s0] + ftb*vv[s0+1] + ftc*vv[s0+2];
    }

    // full Q column on every lane: VALU quad-sum (in place; C already folded)
    #pragma unroll
    for (int i=0;i<16;i++) Qf[i] = quadsum(Qf[i]);
    const float qv = rc + quadsum(qf);

    // Quu/qu via readlane from columns 12..15 (lanes 48,52,56,60) -> SGPRs
    float a00=readlanef(Qf[12],48),a01=readlanef(Qf[12],52),a02=readlanef(Qf[12],56),a03=readlanef(Qf[12],60);
    float a10=readlanef(Qf[13],48),a11=readlanef(Qf[13],52),a12=readlanef(Qf[13],56),a13=readlanef(Qf[13],60);
    float a20=readlanef(Qf[14],48),a21=readlanef(Qf[14],52),a22=readlanef(Qf[14],56),a23=readlanef(Qf[14],60);
    float a30=readlanef(Qf[15],48),a31=readlanef(Qf[15],52),a32=readlanef(Qf[15],56),a33=readlanef(Qf[15],60);
    const float qu0=readlanef(qv,48),qu1=readlanef(qv,52),qu2=readlanef(qv,56),qu3=readlanef(qv,60);

    // K RHS (per-lane, valid for l<12; others unused)
    float b0=-Qf[12],b1=-Qf[13],b2=-Qf[14],b3=-Qf[15];
    // 4x4 LU, no pivot (Quu SPD, diag >= 1); factor is wave-uniform
    const float i0=1.0f/a00;
    const float m10=a10*i0,m20=a20*i0,m30=a30*i0;
    a11-=m10*a01;a12-=m10*a02;a13-=m10*a03;
    a21-=m20*a01;a22-=m20*a02;a23-=m20*a03;
    a31-=m30*a01;a32-=m30*a02;a33-=m30*a03;
    b1-=m10*b0;b2-=m20*b0;b3-=m30*b0;
    const float i1=1.0f/a11;
    const float m21=a21*i1,m31=a31*i1;
    a22-=m21*a12;a23-=m21*a13;
    a32-=m31*a12;a33-=m31*a13;
    b2-=m21*b1;b3-=m31*b1;
    const float i2=1.0f/a22;
    const float m32=a32*i2;
    a33-=m32*a23;
    b3-=m32*b2;
    const float X3=b3/a33;
    const float X2=(b2-a23*X3)*i2;
    const float X1=(b1-a12*X2-a13*X3)*i1;
    const float X0=(b0-a01*X1-a02*X2-a03*X3)*i0;
    // k RHS (uniform)
    float c0=-qu0,c1=-qu1,c2=-qu2,c3=-qu3;
    c1-=m10*c0;c2-=m20*c0;c3-=m30*c0;
    c2-=m21*c1;c3-=m31*c1;
    c3-=m32*c2;
    const float k3=c3/a33;
    const float k2v=(c2-a23*k3)*i2;
    const float k1=(c1-a12*k2v-a13*k3)*i1;
    const float k0=(c0-a01*k1-a02*k2v-a03*k3)*i0;

    if (qd==0)
      storeK<KMODE>(wsv, (size_t)tt*BB+b, l,
                    l<12?X0:k0, l<12?X1:k1, l<12?X2:k2v, l<12?X3:k3);

    // Vn: base_j = Q[3qd+j][l] (select, static idx); Qxu via shfl from
    // lane 48+4r+qd (its base_j == Q[3qd+j][12+r])
    const float base0 = qd==0?Qf[0]:qd==1?Qf[3]:qd==2?Qf[6]:Qf[9];
    const float base1 = qd==0?Qf[1]:qd==1?Qf[4]:qd==2?Qf[7]:Qf[10];
    const float base2 = qd==0?Qf[2]:qd==1?Qf[5]:qd==2?Qf[8]:Qf[11];
    float vn0=base0, vn1=base1, vn2=base2;
    #pragma unroll
    for (int r=0;r<4;r++){
      const float Xr = r==0?X0:r==1?X1:r==2?X2:X3;
      vn0 += __shfl(base0, 48+4*r+qd, 64) * Xr;
      vn1 += __shfl(base1, 48+4*r+qd, 64) * Xr;
      vn2 += __shfl(base2, 48+4*r+qd, 64) * Xr;
    }
    if (l<12){
      const int i0i=3*qd;
      Vb[l*12+i0i]=vn0; Vb[l*12+i0i+1]=vn1; Vb[l*12+i0i+2]=vn2;
      if (qd==0)
        vv[l] = qv + Qf[12]*k0 + Qf[13]*k1 + Qf[14]*k2v + Qf[15]*k3;
    }
    // V/vv/Fl hazards vs next iter: covered by next iter's FENCE
  }

  // drain K/k global stores before forward reads them
  asm volatile("s_waitcnt vmcnt(0)" ::: "memory");

  // ================= forward rollout (quarter-indexed) =================
  const int fl = lane & 15;      // column
  const int g4 = lane >> 4;      // row-quarter (group 0 = lanes 0-15)

  float xj = (g4==0 && fl<12)? xinit[(size_t)b*12+fl] : 0.f;
  double costacc=0.0;

  float4 sCa; float sc2_;
  float4 sF0=make_float4(0,0,0,0),sF1=sF0,sF2=sF0,sF3=sF0; float sf_=0.f;
  float4 sK=make_float4(0,0,0,0); float sk_=0.f;
  {
    const float4* pc=(const float4*)(Cg + (size_t)b*256 + fl*16);
    sCa=pc[g4];                      // C col fl, rows [4g4,4g4+4)
    sc2_=cg[(size_t)b*16+fl];
    if (g4==0 && fl<12){
      const float4* pf=(const float4*)(Fg + (size_t)b*192 + fl*16);
      sF0=pf[0];sF1=pf[1];sF2=pf[2];sF3=pf[3];
      sf_=fg[(size_t)b*12+fl];
      sK=loadKcol<KMODE>(wsv,(size_t)b,fl);
    }
    if (g4==0 && fl>=12) sk_=loadkk<KMODE>(wsv,(size_t)b,fl-12);
  }

  for (int t=0;t<TT;t++){
    float4 Ca=sCa; float rc=sc2_;
    float4 F0=sF0,F1=sF1,F2=sF2,F3=sF3; float rf=sf_;
    float4 K4=sK; float kl=sk_;

    if (t+1<TT){
      const size_t of=((size_t)(t+1)*BB + b);
      const float4* pc=(const float4*)(Cg + of*256 + fl*16);
      sCa=pc[g4];
      sc2_=cg[of*16+fl];
      if (g4==0 && fl<12){
        sK=loadKcol<KMODE>(wsv,of,fl);
        if (t+1<TT-1){
          const float4* pf=(const float4*)(Fg + of*192 + fl*16);
          sF0=pf[0];sF1=pf[1];sF2=pf[2];sF3=pf[3];
          sf_=fg[of*12+fl];
        }
      }
      if (g4==0 && fl>=12) sk_=loadkk<KMODE>(wsv,of,fl-12);
    }

    // u = K x + k : 16-lane DPP reduce on row 0 (lanes 0-15)
    float pr0=0.f,pr1=0.f,pr2=0.f,pr3=0.f;
    if (g4==0 && fl<12){ pr0=K4.x*xj; pr1=K4.y*xj; pr2=K4.z*xj; pr3=K4.w*xj; }
    pr0=reduce16_dpp(pr0); pr1=reduce16_dpp(pr1);
    pr2=reduce16_dpp(pr2); pr3=reduce16_dpp(pr3);

    float* tbuf = tb + (t&1)*16;
    float tauj=0.f;
    if (g4==0){
      if (fl<12) tauj=xj;
      else {
        const float ur=(fl==12)?pr0:(fl==13)?pr1:(fl==14)?pr2:pr3;
        tauj=ur+kl;
      }
      tbuf[fl]=tauj;
    }
    FENCE(); // tau staged (hardware fence: R8 lesson)

    const float taul = tbuf[fl];
    const float4 tq = ((const float4*)tbuf)[g4];    // tau rows [4g4,4g4+4)

    // cost partial: 0.5*tau_fl * sum_{j in quarter} C[j][fl] tau_j (+ c term on g4==0)
    const float dot_p = Ca.x*tq.x + Ca.y*tq.y + Ca.z*tq.z + Ca.w*tq.w;
    costacc += (double)( taul*0.5f*dot_p + (g4==0 ? taul*rc : 0.f) );

    if (g4==0){
      if (fl<12) out[(size_t)t*BB*12 + (size_t)b*12 + fl] = xj;
      else       out[(size_t)TT*BB*12 + (size_t)t*BB*4 + (size_t)b*4 + (fl-12)] = tauj;
    }

    if (t<TT-1 && g4==0 && fl<12){
      const float4* tp=(const float4*)tbuf;
      const float4 t0=tp[0],t1=tp[1],t2=tp[2],t3=tp[3];
      xj = rf
         + F0.x*t0.x+F0.y*t0.y+F0.z*t0.z+F0.w*t0.w
         + F1.x*t1.x+F1.y*t1.y+F1.z*t1.z+F1.w*t1.w
         + F2.x*t2.x+F2.y*t2.y+F2.z*t2.z+F2.w*t2.w
         + F3.x*t3.x+F3.y*t3.y+F3.z*t3.z+F3.w*t3.w;
    }
    // tau WAR across iters: ping-pong
  }

  costacc+=__shfl_xor(costacc,1,64);  costacc+=__shfl_xor(costacc,2,64);
  costacc+=__shfl_xor(costacc,4,64);  costacc+=__shfl_xor(costacc,8,64);
  costacc+=__shfl_xor(costacc,16,64); costacc+=__shfl_xor(costacc,32,64);
  if (lane==0) out[(size_t)TT*BB*16 + b]=(float)costacc;
}

extern "C" void kernel_launch(void* const* d_in, const int* in_sizes, int n_in,
                              void* d_out, int out_size, void* d_ws, size_t ws_size,
                              hipStream_t stream){
  (void)in_sizes; (void)n_in; (void)out_size;
  const float* xinit=(const float*)d_in[0];
  const float* C    =(const float*)d_in[1];
  const float* c    =(const float*)d_in[2];
  const float* F    =(const float*)d_in[3];
  const float* f    =(const float*)d_in[4];
  const size_t need_f32 = (size_t)TT*BB*52*sizeof(float);   // 85.2 MB
  if (ws_size >= need_f32){
    lqr_fused<0><<<dim3(BB/4), dim3(256), 0, stream>>>(xinit,C,c,F,f,(float*)d_out,d_ws);
  } else {
    lqr_fused<1><<<dim3(BB/4), dim3(256), 0, stream>>>(xinit,C,c,F,f,(float*)d_out,d_ws);
  }
}

// Round 14
// 440.808 us; speedup vs baseline: 1.8953x; 1.0519x over previous
//
#include <hip/hip_runtime.h>
#include <hip/hip_fp16.h>

#define TT 100
#define BB 4096
#define GS 488   // floats per batch blob

// per-batch float layout:
//   V   [0,144)    12x12 value matrix, stored transposed (V[l*12+i]=Vn[i][l]);
//                  read as rows via symmetry (proven R11-R13)
//   Fl  [144,384)  12 rows x stride 20
//   vv  [384,396)  v
//   tb  [396,428)  ft (backward) / 2x16 tau ping-pong (forward)
//
// Lane layout (R14): batch = ONE 64-lane wave. lane = 4*l + qd.
//   l  = lane>>2 : column 0..15
//   qd = lane&3  : owns COMPLETE Q rows [4qd,4qd+4) of column l (row-partition;
//                  R13's s-partition needed 17 quad-sums/step — now 1).
// W is s-partitioned (3/lane) then all-gathered via 12 quad_perm broadcasts.
// Quu/qu: readlane. K-RHS: quad_perm(0xFF) bcast. ONE lgkm fence per step.

#define FENCE() asm volatile("s_waitcnt lgkmcnt(0)" ::: "memory")

template<int CTRL>
__device__ __forceinline__ float qbcast(float x){  // quad_perm broadcast (VALU)
  return __int_as_float(__builtin_amdgcn_update_dpp(0, __float_as_int(x), CTRL, 0xF, 0xF, true));
}
// sum over own quad — pure VALU
__device__ __forceinline__ float quadsum(float x){
  int a = __builtin_amdgcn_update_dpp(0, __float_as_int(x), 0xB1, 0xF, 0xF, true);
  x += __int_as_float(a);
  int c = __builtin_amdgcn_update_dpp(0, __float_as_int(x), 0x4E, 0xF, 0xF, true);
  x += __int_as_float(c);
  return x;
}
__device__ __forceinline__ float readlanef(float x, int srclane){
  return __int_as_float(__builtin_amdgcn_readlane(__float_as_int(x), srclane));
}
template<int CTRL>
__device__ __forceinline__ float ror_add(float x){
  int r = __builtin_amdgcn_update_dpp(0, __float_as_int(x), CTRL, 0xF, 0xF, true);
  return x + __int_as_float(r);
}
__device__ __forceinline__ float reduce16_dpp(float x){
  x = ror_add<0x128>(x); x = ror_add<0x124>(x);
  x = ror_add<0x122>(x); x = ror_add<0x121>(x);
  return x;
}

template<int KMODE>
__device__ __forceinline__ void storeK(void* wsv, size_t of, int l, float X0,float X1,float X2,float X3){
  if (KMODE==0){
    float* wsb=(float*)wsv + of*52;
    if (l<12)       ((float4*)wsb)[l]  = make_float4(X0,X1,X2,X3);
    else if (l==12) ((float4*)wsb)[12] = make_float4(X0,X1,X2,X3);
  } else {
    __half* wsb=(__half*)wsv + of*52;
    if (l<12){
      wsb[l*4+0]=__float2half(X0); wsb[l*4+1]=__float2half(X1);
      wsb[l*4+2]=__float2half(X2); wsb[l*4+3]=__float2half(X3);
    } else if (l==12){
      wsb[48]=__float2half(X0); wsb[49]=__float2half(X1);
      wsb[50]=__float2half(X2); wsb[51]=__float2half(X3);
    }
  }
}
template<int KMODE>
__device__ __forceinline__ float4 loadKcol(const void* wsv, size_t of, int l){
  if (KMODE==0) return ((const float4*)((const float*)wsv + of*52))[l];
  const __half* p=(const __half*)wsv + of*52 + l*4;
  return make_float4(__half2float(p[0]),__half2float(p[1]),__half2float(p[2]),__half2float(p[3]));
}
template<int KMODE>
__device__ __forceinline__ float loadkk(const void* wsv, size_t of, int r){
  if (KMODE==0) return ((const float*)wsv)[of*52+48+r];
  return __half2float(((const __half*)wsv)[of*52+48+r]);
}

template<int KMODE>
__global__ __launch_bounds__(256)
void lqr_fused(const float* __restrict__ xinit,
               const float* __restrict__ Cg,
               const float* __restrict__ cg,
               const float* __restrict__ Fg,
               const float* __restrict__ fg,
               float* __restrict__ out,
               void* __restrict__ wsv)
{
  __shared__ float smem[GS*4];
  const int tid  = threadIdx.x;
  const int lane = tid & 63;
  const int wv   = tid >> 6;
  const int b    = blockIdx.x*4 + wv;
  const int l    = lane >> 2;
  const int qd   = lane & 3;

  float* __restrict__ Vb = smem + wv*GS;
  float* __restrict__ Fl = Vb + 144;
  float* __restrict__ vv = Vb + 384;
  float* __restrict__ tb = Vb + 396;

  // zero V (qd<3 own rows [4qd,4qd+4) of column l) and vv (qd==3)
  if (l<12){
    if (qd<3) *(float4*)(Vb + l*12 + 4*qd) = make_float4(0,0,0,0);
    else vv[l]=0.f;
  }

  // ================= backward Riccati =================
  float4 sCq; float sc_;
  float4 sFst=make_float4(0,0,0,0); float sftv=0.f;
  {
    const size_t of = ((size_t)(TT-1)*BB + b);
    sCq = ((const float4*)(Cg + of*256 + l*16))[qd];   // C col l, rows [4qd,4qd+4)
    sc_ = cg[of*16+l];
  }

  for (int tt=TT-1; tt>=0; --tt){
    const bool hasF = (tt < TT-1);
    const float4 Cq=sCq; const float rc=sc_;
    const float4 Fst=sFst; const float ftv=sftv;

    if (hasF){
      if (lane<48) *(float4*)(Fl + l*20 + 4*qd) = Fst;  // row l, cols [4qd,4qd+4)
      if (qd==0 && l<12) tb[l]=ftv;
    }
    FENCE(); // the only backward fence: F/ft staged; prev-iter V/vv visible

    if (tt>0){
      const size_t of = ((size_t)(tt-1)*BB + b);
      sCq = ((const float4*)(Cg + of*256 + l*16))[qd];
      sc_ = cg[of*16+l];
      if (lane<48) sFst = ((const float4*)(Fg + of*192))[lane];
      if (qd==0 && l<12) sftv = fg[of*12+l];
    }

    // own 4 complete Q rows; C quarter folds directly (rows match ownership)
    float Qr0=Cq.x, Qr1=Cq.y, Qr2=Cq.z, Qr3=Cq.w;
    float qf=0.f;
    if (hasF){
      float Ftj[12];
      #pragma unroll
      for (int t=0;t<12;t++) Ftj[t]=Fl[t*20+l];   // F column l
      const int s0=3*qd;
      float W0,W1,W2;
      {
        const float4* vr0=(const float4*)(Vb+(s0+0)*12);
        const float4* vr1=(const float4*)(Vb+(s0+1)*12);
        const float4* vr2=(const float4*)(Vb+(s0+2)*12);
        float4 a0=vr0[0],a1=vr0[1],a2=vr0[2];
        W0 = a0.x*Ftj[0]+a0.y*Ftj[1]+a0.z*Ftj[2]+a0.w*Ftj[3]
           + a1.x*Ftj[4]+a1.y*Ftj[5]+a1.z*Ftj[6]+a1.w*Ftj[7]
           + a2.x*Ftj[8]+a2.y*Ftj[9]+a2.z*Ftj[10]+a2.w*Ftj[11];
        float4 b0=vr1[0],b1=vr1[1],b2=vr1[2];
        W1 = b0.x*Ftj[0]+b0.y*Ftj[1]+b0.z*Ftj[2]+b0.w*Ftj[3]
           + b1.x*Ftj[4]+b1.y*Ftj[5]+b1.z*Ftj[6]+b1.w*Ftj[7]
           + b2.x*Ftj[8]+b2.y*Ftj[9]+b2.z*Ftj[10]+b2.w*Ftj[11];
        float4 c0=vr2[0],c1=vr2[1],c2=vr2[2];
        W2 = c0.x*Ftj[0]+c0.y*Ftj[1]+c0.z*Ftj[2]+c0.w*Ftj[3]
           + c1.x*Ftj[4]+c1.y*Ftj[5]+c1.z*Ftj[6]+c1.w*Ftj[7]
           + c2.x*Ftj[8]+c2.y*Ftj[9]+c2.z*Ftj[10]+c2.w*Ftj[11];
      }
      // all-gather W across the quad (12 VALU quad_perm broadcasts)
      float Wf[12];
      Wf[0] =qbcast<0x00>(W0); Wf[1] =qbcast<0x00>(W1); Wf[2] =qbcast<0x00>(W2);
      Wf[3] =qbcast<0x55>(W0); Wf[4] =qbcast<0x55>(W1); Wf[5] =qbcast<0x55>(W2);
      Wf[6] =qbcast<0xAA>(W0); Wf[7] =qbcast<0xAA>(W1); Wf[8] =qbcast<0xAA>(W2);
      Wf[9] =qbcast<0xFF>(W0); Wf[10]=qbcast<0xFF>(W1); Wf[11]=qbcast<0xFF>(W2);
      // complete own 4 rows: Q[4qd+j][l] += sum_s F[s][4qd+j] * W[s]
      #pragma unroll
      for (int s=0;s<12;s++){
        const float4 f4 = *(const float4*)(Fl + s*20 + 4*qd);
        Qr0 += f4.x*Wf[s]; Qr1 += f4.y*Wf[s];
        Qr2 += f4.z*Wf[s]; Qr3 += f4.w*Wf[s];
      }
      // q partial over own s-range (static-index Ftj selects, rule #20)
      qf = W0*tb[s0] + W1*tb[s0+1] + W2*tb[s0+2];
      const float fta = qd==0?Ftj[0]:qd==1?Ftj[3]:qd==2?Ftj[6]:Ftj[9];
      const float ftb = qd==0?Ftj[1]:qd==1?Ftj[4]:qd==2?Ftj[7]:Ftj[10];
      const float ftc = qd==0?Ftj[2]:qd==1?Ftj[5]:qd==2?Ftj[8]:Ftj[11];
      qf += fta*vv[s0] + ftb*vv[s0+1] + ftc*vv[s0+2];
    }
    const float qv = rc + quadsum(qf);   // the ONLY quadsum left

    // Quu via readlane: column 12+c lives on lane 51+4c (its Qr = rows 12..15)
    float a00=readlanef(Qr0,51),a01=readlanef(Qr0,55),a02=readlanef(Qr0,59),a03=readlanef(Qr0,63);
    float a10=readlanef(Qr1,51),a11=readlanef(Qr1,55),a12=readlanef(Qr1,59),a13=readlanef(Qr1,63);
    float a20=readlanef(Qr2,51),a21=readlanef(Qr2,55),a22=readlanef(Qr2,59),a23=readlanef(Qr2,63);
    float a30=readlanef(Qr3,51),a31=readlanef(Qr3,55),a32=readlanef(Qr3,59),a33=readlanef(Qr3,63);
    const float qu0=readlanef(qv,48),qu1=readlanef(qv,52),qu2=readlanef(qv,56),qu3=readlanef(qv,60);

    // K RHS: rows 12..15 of own column l — quad broadcast from sub-lane 3
    const float b0=-qbcast<0xFF>(Qr0), b1=-qbcast<0xFF>(Qr1),
                b2=-qbcast<0xFF>(Qr2), b3=-qbcast<0xFF>(Qr3);
    float bb0=b0,bb1=b1,bb2=b2,bb3=b3;

    // 4x4 LU, no pivot (Quu SPD, diag >= 1); factor wave-uniform
    const float i0=1.0f/a00;
    const float m10=a10*i0,m20=a20*i0,m30=a30*i0;
    a11-=m10*a01;a12-=m10*a02;a13-=m10*a03;
    a21-=m20*a01;a22-=m20*a02;a23-=m20*a03;
    a31-=m30*a01;a32-=m30*a02;a33-=m30*a03;
    bb1-=m10*bb0;bb2-=m20*bb0;bb3-=m30*bb0;
    const float i1=1.0f/a11;
    const float m21=a21*i1,m31=a31*i1;
    a22-=m21*a12;a23-=m21*a13;
    a32-=m31*a12;a33-=m31*a13;
    bb2-=m21*bb1;bb3-=m31*bb1;
    const float i2=1.0f/a22;
    const float m32=a32*i2;
    a33-=m32*a23;
    bb3-=m32*bb2;
    const float X3=bb3/a33;
    const float X2=(bb2-a23*X3)*i2;
    const float X1=(bb1-a12*X2-a13*X3)*i1;
    const float X0=(bb0-a01*X1-a02*X2-a03*X3)*i0;
    // k RHS (wave-uniform)
    float c0=-qu0,c1=-qu1,c2=-qu2,c3=-qu3;
    c1-=m10*c0;c2-=m20*c0;c3-=m30*c0;
    c2-=m21*c1;c3-=m31*c1;
    c3-=m32*c2;
    const float k3=c3/a33;
    const float k2v=(c2-a23*k3)*i2;
    const float k1=(c1-a12*k2v-a13*k3)*i1;
    const float k0=(c0-a01*k1-a02*k2v-a03*k3)*i0;

    if (qd==0)
      storeK<KMODE>(wsv, (size_t)tt*BB+b, l,
                    l<12?X0:k0, l<12?X1:k1, l<12?X2:k2v, l<12?X3:k3);

    // Vn for own rows: Qxu[4qd+j][r] = Q[4qd+j][12+r] lives on lane 48+4r+qd, reg j
    float vn0=Qr0, vn1=Qr1, vn2=Qr2, vn3=Qr3;
    #pragma unroll
    for (int r=0;r<4;r++){
      const float Xr = r==0?X0:r==1?X1:r==2?X2:X3;
      vn0 += __shfl(Qr0, 48+4*r+qd, 64) * Xr;
      vn1 += __shfl(Qr1, 48+4*r+qd, 64) * Xr;
      vn2 += __shfl(Qr2, 48+4*r+qd, 64) * Xr;
      vn3 += __shfl(Qr3, 48+4*r+qd, 64) * Xr;
    }
    if (l<12){
      if (qd<3){
        // transposed store, one b128 (V[l*12+4qd .. +4) = rows 4qd..4qd+3)
        *(float4*)(Vb + l*12 + 4*qd) = make_float4(vn0,vn1,vn2,vn3);
      } else {
        // qd==3 owns rows 12..15 = Qc[12..15] -> vn via Q symmetry
        vv[l] = qv + Qr0*k0 + Qr1*k1 + Qr2*k2v + Qr3*k3;
      }
    }
    // V/vv/Fl hazards vs next iter: covered by next iter's FENCE
  }

  // drain K/k global stores before forward reads them
  asm volatile("s_waitcnt vmcnt(0)" ::: "memory");

  // ================= forward rollout (R13 verbatim) =================
  const int fl = lane & 15;
  const int g4 = lane >> 4;

  float xj = (g4==0 && fl<12)? xinit[(size_t)b*12+fl] : 0.f;
  double costacc=0.0;

  float4 sCa; float sc2_;
  float4 sF0=make_float4(0,0,0,0),sF1=sF0,sF2=sF0,sF3=sF0; float sf_=0.f;
  float4 sK=make_float4(0,0,0,0); float sk_=0.f;
  {
    const float4* pc=(const float4*)(Cg + (size_t)b*256 + fl*16);
    sCa=pc[g4];
    sc2_=cg[(size_t)b*16+fl];
    if (g4==0 && fl<12){
      const float4* pf=(const float4*)(Fg + (size_t)b*192 + fl*16);
      sF0=pf[0];sF1=pf[1];sF2=pf[2];sF3=pf[3];
      sf_=fg[(size_t)b*12+fl];
      sK=loadKcol<KMODE>(wsv,(size_t)b,fl);
    }
    if (g4==0 && fl>=12) sk_=loadkk<KMODE>(wsv,(size_t)b,fl-12);
  }

  for (int t=0;t<TT;t++){
    float4 Ca=sCa; float rc=sc2_;
    float4 F0=sF0,F1=sF1,F2=sF2,F3=sF3; float rf=sf_;
    float4 K4=sK; float kl=sk_;

    if (t+1<TT){
      const size_t of=((size_t)(t+1)*BB + b);
      const float4* pc=(const float4*)(Cg + of*256 + fl*16);
      sCa=pc[g4];
      sc2_=cg[of*16+fl];
      if (g4==0 && fl<12){
        sK=loadKcol<KMODE>(wsv,of,fl);
        if (t+1<TT-1){
          const float4* pf=(const float4*)(Fg + of*192 + fl*16);
          sF0=pf[0];sF1=pf[1];sF2=pf[2];sF3=pf[3];
          sf_=fg[of*12+fl];
        }
      }
      if (g4==0 && fl>=12) sk_=loadkk<KMODE>(wsv,of,fl-12);
    }

    float pr0=0.f,pr1=0.f,pr2=0.f,pr3=0.f;
    if (g4==0 && fl<12){ pr0=K4.x*xj; pr1=K4.y*xj; pr2=K4.z*xj; pr3=K4.w*xj; }
    pr0=reduce16_dpp(pr0); pr1=reduce16_dpp(pr1);
    pr2=reduce16_dpp(pr2); pr3=reduce16_dpp(pr3);

    float* tbuf = tb + (t&1)*16;
    float tauj=0.f;
    if (g4==0){
      if (fl<12) tauj=xj;
      else {
        const float ur=(fl==12)?pr0:(fl==13)?pr1:(fl==14)?pr2:pr3;
        tauj=ur+kl;
      }
      tbuf[fl]=tauj;
    }
    FENCE();

    const float taul = tbuf[fl];
    const float4 tq = ((const float4*)tbuf)[g4];

    const float dot_p = Ca.x*tq.x + Ca.y*tq.y + Ca.z*tq.z + Ca.w*tq.w;
    costacc += (double)( taul*0.5f*dot_p + (g4==0 ? taul*rc : 0.f) );

    if (g4==0){
      if (fl<12) out[(size_t)t*BB*12 + (size_t)b*12 + fl] = xj;
      else       out[(size_t)TT*BB*12 + (size_t)t*BB*4 + (size_t)b*4 + (fl-12)] = tauj;
    }

    if (t<TT-1 && g4==0 && fl<12){
      const float4* tp=(const float4*)tbuf;
      const float4 t0=tp[0],t1=tp[1],t2=tp[2],t3=tp[3];
      xj = rf
         + F0.x*t0.x+F0.y*t0.y+F0.z*t0.z+F0.w*t0.w
         + F1.x*t1.x+F1.y*t1.y+F1.z*t1.z+F1.w*t1.w
         + F2.x*t2.x+F2.y*t2.y+F2.z*t2.z+F2.w*t2.w
         + F3.x*t3.x+F3.y*t3.y+F3.z*t3.z+F3.w*t3.w;
    }
  }

  costacc+=__shfl_xor(costacc,1,64);  costacc+=__shfl_xor(costacc,2,64);
  costacc+=__shfl_xor(costacc,4,64);  costacc+=__shfl_xor(costacc,8,64);
  costacc+=__shfl_xor(costacc,16,64); costacc+=__shfl_xor(costacc,32,64);
  if (lane==0) out[(size_t)TT*BB*16 + b]=(float)costacc;
}

extern "C" void kernel_launch(void* const* d_in, const int* in_sizes, int n_in,
                              void* d_out, int out_size, void* d_ws, size_t ws_size,
                              hipStream_t stream){
  (void)in_sizes; (void)n_in; (void)out_size;
  const float* xinit=(const float*)d_in[0];
  const float* C    =(const float*)d_in[1];
  const float* c    =(const float*)d_in[2];
  const float* F    =(const float*)d_in[3];
  const float* f    =(const float*)d_in[4];
  const size_t need_f32 = (size_t)TT*BB*52*sizeof(float);   // 85.2 MB
  if (ws_size >= need_f32){
    lqr_fused<0><<<dim3(BB/4), dim3(256), 0, stream>>>(xinit,C,c,F,f,(float*)d_out,d_ws);
  } else {
    lqr_fused<1><<<dim3(BB/4), dim3(256), 0, stream>>>(xinit,C,c,F,f,(float*)d_out,d_ws);
  }
}

// Round 15
// 427.703 us; speedup vs baseline: 1.9534x; 1.0306x over previous
//
#include <hip/hip_runtime.h>
#include <hip/hip_fp16.h>

#define TT 100
#define BB 4096
#define GS 488   // floats per batch blob

// per-batch float layout:
//   V   [0,144)    12x12 value matrix, stored transposed (V[l*12+i]=Vn[i][l]);
//                  read as rows via symmetry (proven R11-R14)
//   Fl  [144,384)  12 rows x stride 20
//   vv  [384,396)  v
//   tb  [396,428)  ft (backward) / 2x16 tau ping-pong (forward)
//
// Lane layout (R14/R15): batch = ONE 64-lane wave. lane = 4*l + qd.
//   l = lane>>2 (column), qd = lane&3 (owns Q rows [4qd,4qd+4) of column l).
// R15 vs R14 (logic identical): (1) all 6 LU/solve divisions -> raw v_rcp_f32
// (IEEE div was ~10-12 VALU instrs each; Quu diag>=1, rcp err ~1e-7 vs
// margin 0.03/6.04); (2) global streams strength-reduced to walking pointers
// (were per-step 64-bit mul/shift chains x5 streams in both loops).

#define FENCE() asm volatile("s_waitcnt lgkmcnt(0)" ::: "memory")

__device__ __forceinline__ float frcp(float x){ return __builtin_amdgcn_rcpf(x); }

template<int CTRL>
__device__ __forceinline__ float qbcast(float x){
  return __int_as_float(__builtin_amdgcn_update_dpp(0, __float_as_int(x), CTRL, 0xF, 0xF, true));
}
__device__ __forceinline__ float quadsum(float x){
  int a = __builtin_amdgcn_update_dpp(0, __float_as_int(x), 0xB1, 0xF, 0xF, true);
  x += __int_as_float(a);
  int c = __builtin_amdgcn_update_dpp(0, __float_as_int(x), 0x4E, 0xF, 0xF, true);
  x += __int_as_float(c);
  return x;
}
__device__ __forceinline__ float readlanef(float x, int srclane){
  return __int_as_float(__builtin_amdgcn_readlane(__float_as_int(x), srclane));
}
template<int CTRL>
__device__ __forceinline__ float ror_add(float x){
  int r = __builtin_amdgcn_update_dpp(0, __float_as_int(x), CTRL, 0xF, 0xF, true);
  return x + __int_as_float(r);
}
__device__ __forceinline__ float reduce16_dpp(float x){
  x = ror_add<0x128>(x); x = ror_add<0x124>(x);
  x = ror_add<0x122>(x); x = ror_add<0x121>(x);
  return x;
}

template<int KMODE>
__device__ __forceinline__ void storeK(void* wsb_, int l, float X0,float X1,float X2,float X3){
  if (KMODE==0){
    float* wsb=(float*)wsb_;
    if (l<12)       ((float4*)wsb)[l]  = make_float4(X0,X1,X2,X3);
    else if (l==12) ((float4*)wsb)[12] = make_float4(X0,X1,X2,X3);
  } else {
    __half* wsb=(__half*)wsb_;
    if (l<12){
      wsb[l*4+0]=__float2half(X0); wsb[l*4+1]=__float2half(X1);
      wsb[l*4+2]=__float2half(X2); wsb[l*4+3]=__float2half(X3);
    } else if (l==12){
      wsb[48]=__float2half(X0); wsb[49]=__float2half(X1);
      wsb[50]=__float2half(X2); wsb[51]=__float2half(X3);
    }
  }
}
template<int KMODE>
__device__ __forceinline__ float4 loadKcol(const void* wsb_, int l){
  if (KMODE==0) return ((const float4*)wsb_)[l];
  const __half* p=(const __half*)wsb_ + l*4;
  return make_float4(__half2float(p[0]),__half2float(p[1]),__half2float(p[2]),__half2float(p[3]));
}
template<int KMODE>
__device__ __forceinline__ float loadkk(const void* wsb_, int r){
  if (KMODE==0) return ((const float*)wsb_)[48+r];
  return __half2float(((const __half*)wsb_)[48+r]);
}

template<int KMODE>
__global__ __launch_bounds__(256)
void lqr_fused(const float* __restrict__ xinit,
               const float* __restrict__ Cg,
               const float* __restrict__ cg,
               const float* __restrict__ Fg,
               const float* __restrict__ fg,
               float* __restrict__ out,
               void* __restrict__ wsv)
{
  __shared__ float smem[GS*4];
  const int tid  = threadIdx.x;
  const int lane = tid & 63;
  const int wv   = tid >> 6;
  const int b    = blockIdx.x*4 + wv;
  const int l    = lane >> 2;
  const int qd   = lane & 3;

  float* __restrict__ Vb = smem + wv*GS;
  float* __restrict__ Fl = Vb + 144;
  float* __restrict__ vv = Vb + 384;
  float* __restrict__ tb = Vb + 396;

  if (l<12){
    if (qd<3) *(float4*)(Vb + l*12 + 4*qd) = make_float4(0,0,0,0);
    else vv[l]=0.f;
  }

  // ================= backward Riccati =================
  // walking pointers (strength-reduced): all at timestep TT-1 initially
  const size_t of0 = ((size_t)(TT-1)*BB + b);
  const float* pC = Cg + of0*256 + l*16 + 4*qd;           // float4 of C col l, rows [4qd,..)
  const float* pc = cg + of0*16 + l;
  const float* pF = Fg + of0*192 + lane*4;                // float4 (lane<48)
  const float* pf = fg + of0*12 + l;
  char*        pW = (char*)wsv + of0*52*(KMODE==0?4:2);   // batch K/k blob

  float4 sCq; float sc_;
  float4 sFst=make_float4(0,0,0,0); float sftv=0.f;
  sCq = *(const float4*)pC;
  sc_ = *pc;

  for (int tt=TT-1; tt>=0; --tt){
    const bool hasF = (tt < TT-1);
    const float4 Cq=sCq; const float rc=sc_;
    const float4 Fst=sFst; const float ftv=sftv;

    if (hasF){
      if (lane<48) *(float4*)(Fl + l*20 + 4*qd) = Fst;
      if (qd==0 && l<12) tb[l]=ftv;
    }
    FENCE(); // the only backward fence

    if (tt>0){
      pC -= (size_t)BB*256; pc -= (size_t)BB*16;
      sCq = *(const float4*)pC;
      sc_ = *pc;
      if (lane<48){ pF -= (size_t)BB*192; sFst = *(const float4*)pF; }
      if (qd==0 && l<12){ pf -= (size_t)BB*12; sftv = *pf; }
    }

    float Qr0=Cq.x, Qr1=Cq.y, Qr2=Cq.z, Qr3=Cq.w;
    float qf=0.f;
    if (hasF){
      float Ftj[12];
      #pragma unroll
      for (int t=0;t<12;t++) Ftj[t]=Fl[t*20+l];
      const int s0=3*qd;
      float W0,W1,W2;
      {
        const float4* vr0=(const float4*)(Vb+(s0+0)*12);
        const float4* vr1=(const float4*)(Vb+(s0+1)*12);
        const float4* vr2=(const float4*)(Vb+(s0+2)*12);
        float4 a0=vr0[0],a1=vr0[1],a2=vr0[2];
        W0 = a0.x*Ftj[0]+a0.y*Ftj[1]+a0.z*Ftj[2]+a0.w*Ftj[3]
           + a1.x*Ftj[4]+a1.y*Ftj[5]+a1.z*Ftj[6]+a1.w*Ftj[7]
           + a2.x*Ftj[8]+a2.y*Ftj[9]+a2.z*Ftj[10]+a2.w*Ftj[11];
        float4 b0v=vr1[0],b1v=vr1[1],b2v=vr1[2];
        W1 = b0v.x*Ftj[0]+b0v.y*Ftj[1]+b0v.z*Ftj[2]+b0v.w*Ftj[3]
           + b1v.x*Ftj[4]+b1v.y*Ftj[5]+b1v.z*Ftj[6]+b1v.w*Ftj[7]
           + b2v.x*Ftj[8]+b2v.y*Ftj[9]+b2v.z*Ftj[10]+b2v.w*Ftj[11];
        float4 c0v=vr2[0],c1v=vr2[1],c2v=vr2[2];
        W2 = c0v.x*Ftj[0]+c0v.y*Ftj[1]+c0v.z*Ftj[2]+c0v.w*Ftj[3]
           + c1v.x*Ftj[4]+c1v.y*Ftj[5]+c1v.z*Ftj[6]+c1v.w*Ftj[7]
           + c2v.x*Ftj[8]+c2v.y*Ftj[9]+c2v.z*Ftj[10]+c2v.w*Ftj[11];
      }
      float Wf[12];
      Wf[0] =qbcast<0x00>(W0); Wf[1] =qbcast<0x00>(W1); Wf[2] =qbcast<0x00>(W2);
      Wf[3] =qbcast<0x55>(W0); Wf[4] =qbcast<0x55>(W1); Wf[5] =qbcast<0x55>(W2);
      Wf[6] =qbcast<0xAA>(W0); Wf[7] =qbcast<0xAA>(W1); Wf[8] =qbcast<0xAA>(W2);
      Wf[9] =qbcast<0xFF>(W0); Wf[10]=qbcast<0xFF>(W1); Wf[11]=qbcast<0xFF>(W2);
      #pragma unroll
      for (int s=0;s<12;s++){
        const float4 f4 = *(const float4*)(Fl + s*20 + 4*qd);
        Qr0 += f4.x*Wf[s]; Qr1 += f4.y*Wf[s];
        Qr2 += f4.z*Wf[s]; Qr3 += f4.w*Wf[s];
      }
      qf = W0*tb[s0] + W1*tb[s0+1] + W2*tb[s0+2];
      const float fta = qd==0?Ftj[0]:qd==1?Ftj[3]:qd==2?Ftj[6]:Ftj[9];
      const float ftb = qd==0?Ftj[1]:qd==1?Ftj[4]:qd==2?Ftj[7]:Ftj[10];
      const float ftc = qd==0?Ftj[2]:qd==1?Ftj[5]:qd==2?Ftj[8]:Ftj[11];
      qf += fta*vv[s0] + ftb*vv[s0+1] + ftc*vv[s0+2];
    }
    const float qv = rc + quadsum(qf);

    float a00=readlanef(Qr0,51),a01=readlanef(Qr0,55),a02=readlanef(Qr0,59),a03=readlanef(Qr0,63);
    float a10=readlanef(Qr1,51),a11=readlanef(Qr1,55),a12=readlanef(Qr1,59),a13=readlanef(Qr1,63);
    float a20=readlanef(Qr2,51),a21=readlanef(Qr2,55),a22=readlanef(Qr2,59),a23=readlanef(Qr2,63);
    float a30=readlanef(Qr3,51),a31=readlanef(Qr3,55),a32=readlanef(Qr3,59),a33=readlanef(Qr3,63);
    const float qu0=readlanef(qv,48),qu1=readlanef(qv,52),qu2=readlanef(qv,56),qu3=readlanef(qv,60);

    const float b0=-qbcast<0xFF>(Qr0), b1=-qbcast<0xFF>(Qr1),
                b2=-qbcast<0xFF>(Qr2), b3=-qbcast<0xFF>(Qr3);
    float bb0=b0,bb1=b1,bb2=b2,bb3=b3;

    // 4x4 LU, no pivot; all reciprocals via raw v_rcp_f32 (R15)
    const float i0=frcp(a00);
    const float m10=a10*i0,m20=a20*i0,m30=a30*i0;
    a11-=m10*a01;a12-=m10*a02;a13-=m10*a03;
    a21-=m20*a01;a22-=m20*a02;a23-=m20*a03;
    a31-=m30*a01;a32-=m30*a02;a33-=m30*a03;
    bb1-=m10*bb0;bb2-=m20*bb0;bb3-=m30*bb0;
    const float i1=frcp(a11);
    const float m21=a21*i1,m31=a31*i1;
    a22-=m21*a12;a23-=m21*a13;
    a32-=m31*a12;a33-=m31*a13;
    bb2-=m21*bb1;bb3-=m31*bb1;
    const float i2=frcp(a22);
    const float m32=a32*i2;
    a33-=m32*a23;
    bb3-=m32*bb2;
    const float i3=frcp(a33);
    const float X3=bb3*i3;
    const float X2=(bb2-a23*X3)*i2;
    const float X1=(bb1-a12*X2-a13*X3)*i1;
    const float X0=(bb0-a01*X1-a02*X2-a03*X3)*i0;
    float c0=-qu0,c1=-qu1,c2=-qu2,c3=-qu3;
    c1-=m10*c0;c2-=m20*c0;c3-=m30*c0;
    c2-=m21*c1;c3-=m31*c1;
    c3-=m32*c2;
    const float k3=c3*i3;
    const float k2v=(c2-a23*k3)*i2;
    const float k1=(c1-a12*k2v-a13*k3)*i1;
    const float k0=(c0-a01*k1-a02*k2v-a03*k3)*i0;

    if (qd==0)
      storeK<KMODE>(pW, l, l<12?X0:k0, l<12?X1:k1, l<12?X2:k2v, l<12?X3:k3);
    pW -= (size_t)BB*52*(KMODE==0?4:2);

    float vn0=Qr0, vn1=Qr1, vn2=Qr2, vn3=Qr3;
    #pragma unroll
    for (int r=0;r<4;r++){
      const float Xr = r==0?X0:r==1?X1:r==2?X2:X3;
      vn0 += __shfl(Qr0, 48+4*r+qd, 64) * Xr;
      vn1 += __shfl(Qr1, 48+4*r+qd, 64) * Xr;
      vn2 += __shfl(Qr2, 48+4*r+qd, 64) * Xr;
      vn3 += __shfl(Qr3, 48+4*r+qd, 64) * Xr;
    }
    if (l<12){
      if (qd<3){
        *(float4*)(Vb + l*12 + 4*qd) = make_float4(vn0,vn1,vn2,vn3);
      } else {
        vv[l] = qv + Qr0*k0 + Qr1*k1 + Qr2*k2v + Qr3*k3;
      }
    }
  }

  // drain K/k global stores before forward reads them
  asm volatile("s_waitcnt vmcnt(0)" ::: "memory");

  // ================= forward rollout =================
  const int fl = lane & 15;
  const int g4 = lane >> 4;

  float xj = (g4==0 && fl<12)? xinit[(size_t)b*12+fl] : 0.f;
  double costacc=0.0;

  // walking pointers, start at t=0 (of = b)
  const float* qC = Cg + (size_t)b*256 + fl*16 + 4*g4;
  const float* qc = cg + (size_t)b*16 + fl;
  const float* qF = Fg + (size_t)b*192 + fl*16;
  const float* qf2= fg + (size_t)b*12 + fl;
  const char*  qK = (const char*)wsv + (size_t)b*52*(KMODE==0?4:2);

  float4 sCa; float sc2_;
  float4 sF0=make_float4(0,0,0,0),sF1=sF0,sF2=sF0,sF3=sF0; float sf_=0.f;
  float4 sK=make_float4(0,0,0,0); float sk_=0.f;
  {
    sCa = *(const float4*)qC;
    sc2_= *qc;
    if (g4==0 && fl<12){
      const float4* pf4=(const float4*)qF;
      sF0=pf4[0];sF1=pf4[1];sF2=pf4[2];sF3=pf4[3];
      sf_=*qf2;
      sK=loadKcol<KMODE>(qK,fl);
    }
    if (g4==0 && fl>=12) sk_=loadkk<KMODE>(qK,fl-12);
  }

  for (int t=0;t<TT;t++){
    float4 Ca=sCa; float rc=sc2_;
    float4 F0=sF0,F1=sF1,F2=sF2,F3=sF3; float rf=sf_;
    float4 K4=sK; float kl=sk_;

    if (t+1<TT){
      qC += (size_t)BB*256; qc += (size_t)BB*16; qK += (size_t)BB*52*(KMODE==0?4:2);
      sCa = *(const float4*)qC;
      sc2_= *qc;
      if (g4==0 && fl<12){
        sK=loadKcol<KMODE>(qK,fl);
        if (t+1<TT-1){
          qF += (size_t)BB*192; qf2 += (size_t)BB*12;
          const float4* pf4=(const float4*)qF;
          sF0=pf4[0];sF1=pf4[1];sF2=pf4[2];sF3=pf4[3];
          sf_=*qf2;
        }
      }
      if (g4==0 && fl>=12) sk_=loadkk<KMODE>(qK,fl-12);
    }

    float pr0=0.f,pr1=0.f,pr2=0.f,pr3=0.f;
    if (g4==0 && fl<12){ pr0=K4.x*xj; pr1=K4.y*xj; pr2=K4.z*xj; pr3=K4.w*xj; }
    pr0=reduce16_dpp(pr0); pr1=reduce16_dpp(pr1);
    pr2=reduce16_dpp(pr2); pr3=reduce16_dpp(pr3);

    float* tbuf = tb + (t&1)*16;
    float tauj=0.f;
    if (g4==0){
      if (fl<12) tauj=xj;
      else {
        const float ur=(fl==12)?pr0:(fl==13)?pr1:(fl==14)?pr2:pr3;
        tauj=ur+kl;
      }
      tbuf[fl]=tauj;
    }
    FENCE();

    const float taul = tbuf[fl];
    const float4 tq = ((const float4*)tbuf)[g4];

    const float dot_p = Ca.x*tq.x + Ca.y*tq.y + Ca.z*tq.z + Ca.w*tq.w;
    costacc += (double)( taul*0.5f*dot_p + (g4==0 ? taul*rc : 0.f) );

    if (g4==0){
      if (fl<12) out[(size_t)t*BB*12 + (size_t)b*12 + fl] = xj;
      else       out[(size_t)TT*BB*12 + (size_t)t*BB*4 + (size_t)b*4 + (fl-12)] = tauj;
    }

    if (t<TT-1 && g4==0 && fl<12){
      const float4* tp=(const float4*)tbuf;
      const float4 t0=tp[0],t1=tp[1],t2=tp[2],t3=tp[3];
      xj = rf
         + F0.x*t0.x+F0.y*t0.y+F0.z*t0.z+F0.w*t0.w
         + F1.x*t1.x+F1.y*t1.y+F1.z*t1.z+F1.w*t1.w
         + F2.x*t2.x+F2.y*t2.y+F2.z*t2.z+F2.w*t2.w
         + F3.x*t3.x+F3.y*t3.y+F3.z*t3.z+F3.w*t3.w;
    }
  }

  costacc+=__shfl_xor(costacc,1,64);  costacc+=__shfl_xor(costacc,2,64);
  costacc+=__shfl_xor(costacc,4,64);  costacc+=__shfl_xor(costacc,8,64);
  costacc+=__shfl_xor(costacc,16,64); costacc+=__shfl_xor(costacc,32,64);
  if (lane==0) out[(size_t)TT*BB*16 + b]=(float)costacc;
}

extern "C" void kernel_launch(void* const* d_in, const int* in_sizes, int n_in,
                              void* d_out, int out_size, void* d_ws, size_t ws_size,
                              hipStream_t stream){
  (void)in_sizes; (void)n_in; (void)out_size;
  const float* xinit=(const float*)d_in[0];
  const float* C    =(const float*)d_in[1];
  const float* c    =(const float*)d_in[2];
  const float* F    =(const float*)d_in[3];
  const float* f    =(const float*)d_in[4];
  const size_t need_f32 = (size_t)TT*BB*52*sizeof(float);   // 85.2 MB
  if (ws_size >= need_f32){
    lqr_fused<0><<<dim3(BB/4), dim3(256), 0, stream>>>(xinit,C,c,F,f,(float*)d_out,d_ws);
  } else {
    lqr_fused<1><<<dim3(BB/4), dim3(256), 0, stream>>>(xinit,C,c,F,f,(float*)d_out,d_ws);
  }
}

// Round 16
// 422.632 us; speedup vs baseline: 1.9768x; 1.0120x over previous
//
#include <hip/hip_runtime.h>
#include <hip/hip_fp16.h>

#define TT 100
#define BB 4096
#define GS 488   // floats per batch blob (one batch per block now)

// per-batch float layout:
//   V   [0,144)    12x12 value matrix, stored transposed (V[l*12+i]=Vn[i][l]);
//                  read as rows via symmetry (proven R11-R15)
//   Fl  [144,384)  12 rows x stride 20
//   vv  [384,396)  v
//   tb  [396,428)  ft (backward) / 2x16 tau ping-pong (forward)
//
// Lane layout: batch = ONE 64-lane wave. lane = 4*l + qd.
//   l = lane>>2 (column), qd = lane&3 (owns Q rows [4qd,4qd+4) of column l).
// R16 vs R15 (logic identical): block 256->64 (1 wave = 1 batch = 1 block).
// 4096 waves / 1024 SIMDs = 4 waves/SIMD is the problem-fixed ceiling (50%
// occupancy); 4-wave blocks realized only 38.6% due to co-launch/co-drain
// granularity. Single-wave blocks let the scheduler pack/retire waves
// independently.

#define FENCE() asm volatile("s_waitcnt lgkmcnt(0)" ::: "memory")

__device__ __forceinline__ float frcp(float x){ return __builtin_amdgcn_rcpf(x); }

template<int CTRL>
__device__ __forceinline__ float qbcast(float x){
  return __int_as_float(__builtin_amdgcn_update_dpp(0, __float_as_int(x), CTRL, 0xF, 0xF, true));
}
__device__ __forceinline__ float quadsum(float x){
  int a = __builtin_amdgcn_update_dpp(0, __float_as_int(x), 0xB1, 0xF, 0xF, true);
  x += __int_as_float(a);
  int c = __builtin_amdgcn_update_dpp(0, __float_as_int(x), 0x4E, 0xF, 0xF, true);
  x += __int_as_float(c);
  return x;
}
__device__ __forceinline__ float readlanef(float x, int srclane){
  return __int_as_float(__builtin_amdgcn_readlane(__float_as_int(x), srclane));
}
template<int CTRL>
__device__ __forceinline__ float ror_add(float x){
  int r = __builtin_amdgcn_update_dpp(0, __float_as_int(x), CTRL, 0xF, 0xF, true);
  return x + __int_as_float(r);
}
__device__ __forceinline__ float reduce16_dpp(float x){
  x = ror_add<0x128>(x); x = ror_add<0x124>(x);
  x = ror_add<0x122>(x); x = ror_add<0x121>(x);
  return x;
}

template<int KMODE>
__device__ __forceinline__ void storeK(void* wsb_, int l, float X0,float X1,float X2,float X3){
  if (KMODE==0){
    float* wsb=(float*)wsb_;
    if (l<12)       ((float4*)wsb)[l]  = make_float4(X0,X1,X2,X3);
    else if (l==12) ((float4*)wsb)[12] = make_float4(X0,X1,X2,X3);
  } else {
    __half* wsb=(__half*)wsb_;
    if (l<12){
      wsb[l*4+0]=__float2half(X0); wsb[l*4+1]=__float2half(X1);
      wsb[l*4+2]=__float2half(X2); wsb[l*4+3]=__float2half(X3);
    } else if (l==12){
      wsb[48]=__float2half(X0); wsb[49]=__float2half(X1);
      wsb[50]=__float2half(X2); wsb[51]=__float2half(X3);
    }
  }
}
template<int KMODE>
__device__ __forceinline__ float4 loadKcol(const void* wsb_, int l){
  if (KMODE==0) return ((const float4*)wsb_)[l];
  const __half* p=(const __half*)wsb_ + l*4;
  return make_float4(__half2float(p[0]),__half2float(p[1]),__half2float(p[2]),__half2float(p[3]));
}
template<int KMODE>
__device__ __forceinline__ float loadkk(const void* wsb_, int r){
  if (KMODE==0) return ((const float*)wsb_)[48+r];
  return __half2float(((const __half*)wsb_)[48+r]);
}

template<int KMODE>
__global__ __launch_bounds__(64)
void lqr_fused(const float* __restrict__ xinit,
               const float* __restrict__ Cg,
               const float* __restrict__ cg,
               const float* __restrict__ Fg,
               const float* __restrict__ fg,
               float* __restrict__ out,
               void* __restrict__ wsv)
{
  __shared__ float smem[GS];
  const int lane = threadIdx.x & 63;
  const int b    = blockIdx.x;
  const int l    = lane >> 2;
  const int qd   = lane & 3;

  float* __restrict__ Vb = smem;
  float* __restrict__ Fl = Vb + 144;
  float* __restrict__ vv = Vb + 384;
  float* __restrict__ tb = Vb + 396;

  if (l<12){
    if (qd<3) *(float4*)(Vb + l*12 + 4*qd) = make_float4(0,0,0,0);
    else vv[l]=0.f;
  }

  // ================= backward Riccati =================
  const size_t of0 = ((size_t)(TT-1)*BB + b);
  const float* pC = Cg + of0*256 + l*16 + 4*qd;
  const float* pc = cg + of0*16 + l;
  const float* pF = Fg + of0*192 + lane*4;
  const float* pf = fg + of0*12 + l;
  char*        pW = (char*)wsv + of0*52*(KMODE==0?4:2);

  float4 sCq; float sc_;
  float4 sFst=make_float4(0,0,0,0); float sftv=0.f;
  sCq = *(const float4*)pC;
  sc_ = *pc;

  for (int tt=TT-1; tt>=0; --tt){
    const bool hasF = (tt < TT-1);
    const float4 Cq=sCq; const float rc=sc_;
    const float4 Fst=sFst; const float ftv=sftv;

    if (hasF){
      if (lane<48) *(float4*)(Fl + l*20 + 4*qd) = Fst;
      if (qd==0 && l<12) tb[l]=ftv;
    }
    FENCE(); // the only backward fence

    if (tt>0){
      pC -= (size_t)BB*256; pc -= (size_t)BB*16;
      sCq = *(const float4*)pC;
      sc_ = *pc;
      if (lane<48){ pF -= (size_t)BB*192; sFst = *(const float4*)pF; }
      if (qd==0 && l<12){ pf -= (size_t)BB*12; sftv = *pf; }
    }

    float Qr0=Cq.x, Qr1=Cq.y, Qr2=Cq.z, Qr3=Cq.w;
    float qf=0.f;
    if (hasF){
      float Ftj[12];
      #pragma unroll
      for (int t=0;t<12;t++) Ftj[t]=Fl[t*20+l];
      const int s0=3*qd;
      float W0,W1,W2;
      {
        const float4* vr0=(const float4*)(Vb+(s0+0)*12);
        const float4* vr1=(const float4*)(Vb+(s0+1)*12);
        const float4* vr2=(const float4*)(Vb+(s0+2)*12);
        float4 a0=vr0[0],a1=vr0[1],a2=vr0[2];
        W0 = a0.x*Ftj[0]+a0.y*Ftj[1]+a0.z*Ftj[2]+a0.w*Ftj[3]
           + a1.x*Ftj[4]+a1.y*Ftj[5]+a1.z*Ftj[6]+a1.w*Ftj[7]
           + a2.x*Ftj[8]+a2.y*Ftj[9]+a2.z*Ftj[10]+a2.w*Ftj[11];
        float4 b0v=vr1[0],b1v=vr1[1],b2v=vr1[2];
        W1 = b0v.x*Ftj[0]+b0v.y*Ftj[1]+b0v.z*Ftj[2]+b0v.w*Ftj[3]
           + b1v.x*Ftj[4]+b1v.y*Ftj[5]+b1v.z*Ftj[6]+b1v.w*Ftj[7]
           + b2v.x*Ftj[8]+b2v.y*Ftj[9]+b2v.z*Ftj[10]+b2v.w*Ftj[11];
        float4 c0v=vr2[0],c1v=vr2[1],c2v=vr2[2];
        W2 = c0v.x*Ftj[0]+c0v.y*Ftj[1]+c0v.z*Ftj[2]+c0v.w*Ftj[3]
           + c1v.x*Ftj[4]+c1v.y*Ftj[5]+c1v.z*Ftj[6]+c1v.w*Ftj[7]
           + c2v.x*Ftj[8]+c2v.y*Ftj[9]+c2v.z*Ftj[10]+c2v.w*Ftj[11];
      }
      float Wf[12];
      Wf[0] =qbcast<0x00>(W0); Wf[1] =qbcast<0x00>(W1); Wf[2] =qbcast<0x00>(W2);
      Wf[3] =qbcast<0x55>(W0); Wf[4] =qbcast<0x55>(W1); Wf[5] =qbcast<0x55>(W2);
      Wf[6] =qbcast<0xAA>(W0); Wf[7] =qbcast<0xAA>(W1); Wf[8] =qbcast<0xAA>(W2);
      Wf[9] =qbcast<0xFF>(W0); Wf[10]=qbcast<0xFF>(W1); Wf[11]=qbcast<0xFF>(W2);
      #pragma unroll
      for (int s=0;s<12;s++){
        const float4 f4 = *(const float4*)(Fl + s*20 + 4*qd);
        Qr0 += f4.x*Wf[s]; Qr1 += f4.y*Wf[s];
        Qr2 += f4.z*Wf[s]; Qr3 += f4.w*Wf[s];
      }
      qf = W0*tb[s0] + W1*tb[s0+1] + W2*tb[s0+2];
      const float fta = qd==0?Ftj[0]:qd==1?Ftj[3]:qd==2?Ftj[6]:Ftj[9];
      const float ftb = qd==0?Ftj[1]:qd==1?Ftj[4]:qd==2?Ftj[7]:Ftj[10];
      const float ftc = qd==0?Ftj[2]:qd==1?Ftj[5]:qd==2?Ftj[8]:Ftj[11];
      qf += fta*vv[s0] + ftb*vv[s0+1] + ftc*vv[s0+2];
    }
    const float qv = rc + quadsum(qf);

    float a00=readlanef(Qr0,51),a01=readlanef(Qr0,55),a02=readlanef(Qr0,59),a03=readlanef(Qr0,63);
    float a10=readlanef(Qr1,51),a11=readlanef(Qr1,55),a12=readlanef(Qr1,59),a13=readlanef(Qr1,63);
    float a20=readlanef(Qr2,51),a21=readlanef(Qr2,55),a22=readlanef(Qr2,59),a23=readlanef(Qr2,63);
    float a30=readlanef(Qr3,51),a31=readlanef(Qr3,55),a32=readlanef(Qr3,59),a33=readlanef(Qr3,63);
    const float qu0=readlanef(qv,48),qu1=readlanef(qv,52),qu2=readlanef(qv,56),qu3=readlanef(qv,60);

    const float b0=-qbcast<0xFF>(Qr0), b1=-qbcast<0xFF>(Qr1),
                b2=-qbcast<0xFF>(Qr2), b3=-qbcast<0xFF>(Qr3);
    float bb0=b0,bb1=b1,bb2=b2,bb3=b3;

    const float i0=frcp(a00);
    const float m10=a10*i0,m20=a20*i0,m30=a30*i0;
    a11-=m10*a01;a12-=m10*a02;a13-=m10*a03;
    a21-=m20*a01;a22-=m20*a02;a23-=m20*a03;
    a31-=m30*a01;a32-=m30*a02;a33-=m30*a03;
    bb1-=m10*bb0;bb2-=m20*bb0;bb3-=m30*bb0;
    const float i1=frcp(a11);
    const float m21=a21*i1,m31=a31*i1;
    a22-=m21*a12;a23-=m21*a13;
    a32-=m31*a12;a33-=m31*a13;
    bb2-=m21*bb1;bb3-=m31*bb1;
    const float i2=frcp(a22);
    const float m32=a32*i2;
    a33-=m32*a23;
    bb3-=m32*bb2;
    const float i3=frcp(a33);
    const float X3=bb3*i3;
    const float X2=(bb2-a23*X3)*i2;
    const float X1=(bb1-a12*X2-a13*X3)*i1;
    const float X0=(bb0-a01*X1-a02*X2-a03*X3)*i0;
    float c0=-qu0,c1=-qu1,c2=-qu2,c3=-qu3;
    c1-=m10*c0;c2-=m20*c0;c3-=m30*c0;
    c2-=m21*c1;c3-=m31*c1;
    c3-=m32*c2;
    const float k3=c3*i3;
    const float k2v=(c2-a23*k3)*i2;
    const float k1=(c1-a12*k2v-a13*k3)*i1;
    const float k0=(c0-a01*k1-a02*k2v-a03*k3)*i0;

    if (qd==0)
      storeK<KMODE>(pW, l, l<12?X0:k0, l<12?X1:k1, l<12?X2:k2v, l<12?X3:k3);
    pW -= (size_t)BB*52*(KMODE==0?4:2);

    float vn0=Qr0, vn1=Qr1, vn2=Qr2, vn3=Qr3;
    #pragma unroll
    for (int r=0;r<4;r++){
      const float Xr = r==0?X0:r==1?X1:r==2?X2:X3;
      vn0 += __shfl(Qr0, 48+4*r+qd, 64) * Xr;
      vn1 += __shfl(Qr1, 48+4*r+qd, 64) * Xr;
      vn2 += __shfl(Qr2, 48+4*r+qd, 64) * Xr;
      vn3 += __shfl(Qr3, 48+4*r+qd, 64) * Xr;
    }
    if (l<12){
      if (qd<3){
        *(float4*)(Vb + l*12 + 4*qd) = make_float4(vn0,vn1,vn2,vn3);
      } else {
        vv[l] = qv + Qr0*k0 + Qr1*k1 + Qr2*k2v + Qr3*k3;
      }
    }
  }

  // drain K/k global stores before forward reads them
  asm volatile("s_waitcnt vmcnt(0)" ::: "memory");

  // ================= forward rollout =================
  const int fl = lane & 15;
  const int g4 = lane >> 4;

  float xj = (g4==0 && fl<12)? xinit[(size_t)b*12+fl] : 0.f;
  double costacc=0.0;

  const float* qC = Cg + (size_t)b*256 + fl*16 + 4*g4;
  const float* qc = cg + (size_t)b*16 + fl;
  const float* qF = Fg + (size_t)b*192 + fl*16;
  const float* qf2= fg + (size_t)b*12 + fl;
  const char*  qK = (const char*)wsv + (size_t)b*52*(KMODE==0?4:2);

  float4 sCa; float sc2_;
  float4 sF0=make_float4(0,0,0,0),sF1=sF0,sF2=sF0,sF3=sF0; float sf_=0.f;
  float4 sK=make_float4(0,0,0,0); float sk_=0.f;
  {
    sCa = *(const float4*)qC;
    sc2_= *qc;
    if (g4==0 && fl<12){
      const float4* pf4=(const float4*)qF;
      sF0=pf4[0];sF1=pf4[1];sF2=pf4[2];sF3=pf4[3];
      sf_=*qf2;
      sK=loadKcol<KMODE>(qK,fl);
    }
    if (g4==0 && fl>=12) sk_=loadkk<KMODE>(qK,fl-12);
  }

  for (int t=0;t<TT;t++){
    float4 Ca=sCa; float rc=sc2_;
    float4 F0=sF0,F1=sF1,F2=sF2,F3=sF3; float rf=sf_;
    float4 K4=sK; float kl=sk_;

    if (t+1<TT){
      qC += (size_t)BB*256; qc += (size_t)BB*16; qK += (size_t)BB*52*(KMODE==0?4:2);
      sCa = *(const float4*)qC;
      sc2_= *qc;
      if (g4==0 && fl<12){
        sK=loadKcol<KMODE>(qK,fl);
        if (t+1<TT-1){
          qF += (size_t)BB*192; qf2 += (size_t)BB*12;
          const float4* pf4=(const float4*)qF;
          sF0=pf4[0];sF1=pf4[1];sF2=pf4[2];sF3=pf4[3];
          sf_=*qf2;
        }
      }
      if (g4==0 && fl>=12) sk_=loadkk<KMODE>(qK,fl-12);
    }

    float pr0=0.f,pr1=0.f,pr2=0.f,pr3=0.f;
    if (g4==0 && fl<12){ pr0=K4.x*xj; pr1=K4.y*xj; pr2=K4.z*xj; pr3=K4.w*xj; }
    pr0=reduce16_dpp(pr0); pr1=reduce16_dpp(pr1);
    pr2=reduce16_dpp(pr2); pr3=reduce16_dpp(pr3);

    float* tbuf = tb + (t&1)*16;
    float tauj=0.f;
    if (g4==0){
      if (fl<12) tauj=xj;
      else {
        const float ur=(fl==12)?pr0:(fl==13)?pr1:(fl==14)?pr2:pr3;
        tauj=ur+kl;
      }
      tbuf[fl]=tauj;
    }
    FENCE();

    const float taul = tbuf[fl];
    const float4 tq = ((const float4*)tbuf)[g4];

    const float dot_p = Ca.x*tq.x + Ca.y*tq.y + Ca.z*tq.z + Ca.w*tq.w;
    costacc += (double)( taul*0.5f*dot_p + (g4==0 ? taul*rc : 0.f) );

    if (g4==0){
      if (fl<12) out[(size_t)t*BB*12 + (size_t)b*12 + fl] = xj;
      else       out[(size_t)TT*BB*12 + (size_t)t*BB*4 + (size_t)b*4 + (fl-12)] = tauj;
    }

    if (t<TT-1 && g4==0 && fl<12){
      const float4* tp=(const float4*)tbuf;
      const float4 t0=tp[0],t1=tp[1],t2=tp[2],t3=tp[3];
      xj = rf
         + F0.x*t0.x+F0.y*t0.y+F0.z*t0.z+F0.w*t0.w
         + F1.x*t1.x+F1.y*t1.y+F1.z*t1.z+F1.w*t1.w
         + F2.x*t2.x+F2.y*t2.y+F2.z*t2.z+F2.w*t2.w
         + F3.x*t3.x+F3.y*t3.y+F3.z*t3.z+F3.w*t3.w;
    }
  }

  costacc+=__shfl_xor(costacc,1,64);  costacc+=__shfl_xor(costacc,2,64);
  costacc+=__shfl_xor(costacc,4,64);  costacc+=__shfl_xor(costacc,8,64);
  costacc+=__shfl_xor(costacc,16,64); costacc+=__shfl_xor(costacc,32,64);
  if (lane==0) out[(size_t)TT*BB*16 + b]=(float)costacc;
}

extern "C" void kernel_launch(void* const* d_in, const int* in_sizes, int n_in,
                              void* d_out, int out_size, void* d_ws, size_t ws_size,
                              hipStream_t stream){
  (void)in_sizes; (void)n_in; (void)out_size;
  const float* xinit=(const float*)d_in[0];
  const float* C    =(const float*)d_in[1];
  const float* c    =(const float*)d_in[2];
  const float* F    =(const float*)d_in[3];
  const float* f    =(const float*)d_in[4];
  const size_t need_f32 = (size_t)TT*BB*52*sizeof(float);   // 85.2 MB
  if (ws_size >= need_f32){
    lqr_fused<0><<<dim3(BB), dim3(64), 0, stream>>>(xinit,C,c,F,f,(float*)d_out,d_ws);
  } else {
    lqr_fused<1><<<dim3(BB), dim3(64), 0, stream>>>(xinit,C,c,F,f,(float*)d_out,d_ws);
  }
}